// Round 11
// baseline (459.249 us; speedup 1.0000x reference)
//
#include <hip/hip_runtime.h>
#include <hip/hip_bf16.h>
#include <stdint.h>

#define IN_F   4096
#define OUT_F  11008
#define M_DIM  8192          // B*S

// ---------------- 4-phase 256x256 geometry, int8, 32x32x32 MFMA ----------------
#define BM 256
#define BN 256
#define BK 64                  // 64 i8 elems = 64 B per row per K-tile
#define TM (M_DIM / BM)        // 32
#define TN (OUT_F / BN)        // 43
#define NWG (TM * TN)          // 1376
#define KT (IN_F / BK)         // 64 K-tiles
#define KC (IN_F / 16)         // 256 16-B chunks per row
#define HTB (128 * 64)         // half-tile bytes (128 rows x 64 B) = 8 KiB

typedef __attribute__((ext_vector_type(4)))  int   int32x4;
typedef __attribute__((ext_vector_type(16))) int   int32x16;
typedef __attribute__((ext_vector_type(8)))  short short8;
typedef __attribute__((ext_vector_type(4)))  float f32x4;

union Pack8 { __bf16 h[8]; uint4 u; };
union PackI { char c[16]; ::int4 v; };

__device__ inline uint4 pack8_f(float4 f0, float4 f1) {
    Pack8 o;
    o.h[0] = (__bf16)f0.x; o.h[1] = (__bf16)f0.y;
    o.h[2] = (__bf16)f0.z; o.h[3] = (__bf16)f0.w;
    o.h[4] = (__bf16)f1.x; o.h[5] = (__bf16)f1.y;
    o.h[6] = (__bf16)f1.z; o.h[7] = (__bf16)f1.w;
    return o.u;
}

__device__ inline uint4 dequant8(int4 v, float s, float zb) {
    Pack8 o;
    int pv[4] = {v.x, v.y, v.z, v.w};
#pragma unroll
    for (int j = 0; j < 4; ++j) {
        o.h[2 * j]     = (__bf16)fmaf((float)(pv[j] & 15), s, zb);
        o.h[2 * j + 1] = (__bf16)fmaf((float)((pv[j] >> 4) & 15), s, zb);
    }
    return o.u;
}

#define GLOAD_LDS16(g, l)                                                     \
    __builtin_amdgcn_global_load_lds(                                         \
        (const __attribute__((address_space(1))) void*)(g),                   \
        (__attribute__((address_space(3))) void*)(l), 16, 0, 0)

#define BAR()   __builtin_amdgcn_s_barrier()
#define SBAR0() __builtin_amdgcn_sched_barrier(0)
#define VMW(n)  asm volatile("s_waitcnt vmcnt(" #n ")" ::: "memory")

// ---------- preprocessing: x fp32 -> i8 with per-row absmax scale ----------
__global__ __launch_bounds__(256) void quant_x_kernel(const float* __restrict__ x,
        char* __restrict__ xq, float* __restrict__ srow) {
    const int row = blockIdx.x;
    const int t   = threadIdx.x;
    const float4* xr = (const float4*)(x + (size_t)row * IN_F) + t * 4;
    float4 v[4];
    float am = 0.f;
#pragma unroll
    for (int j = 0; j < 4; ++j) {
        v[j] = xr[j];
        am = fmaxf(am, fmaxf(fmaxf(fabsf(v[j].x), fabsf(v[j].y)),
                             fmaxf(fabsf(v[j].z), fabsf(v[j].w))));
    }
#pragma unroll
    for (int off = 32; off; off >>= 1) am = fmaxf(am, __shfl_xor(am, off, 64));
    __shared__ float wm4[4];
    if ((t & 63) == 0) wm4[t >> 6] = am;
    __syncthreads();
    am = fmaxf(fmaxf(wm4[0], wm4[1]), fmaxf(wm4[2], wm4[3]));
    const float qs = am > 0.f ? 127.f / am : 0.f;
    if (t == 0) srow[row] = am > 0.f ? am * (1.f / 127.f) : 0.f;
    PackI o;
#pragma unroll
    for (int j = 0; j < 4; ++j) {
        const float* f = (const float*)&v[j];
#pragma unroll
        for (int e = 0; e < 4; ++e) {
            float q = rintf(f[e] * qs);
            q = fminf(127.f, fmaxf(-127.f, q));
            o.c[j * 4 + e] = (char)(int)q;
        }
    }
    ((::int4*)(xq + (size_t)row * IN_F))[t] = o.v;
}

// ---------- preprocessing: packed int4 W -> i8 (q - zp, EXACT) ----------
__global__ void deqw_i8_kernel(const int* __restrict__ pw, const int* __restrict__ zps,
                               char* __restrict__ wq, int nChunks) {
    int stride = gridDim.x * blockDim.x;
    for (int c = blockIdx.x * blockDim.x + threadIdx.x; c < nChunks; c += stride) {
        int row = c >> 8;          // 256 16-B chunks per row
        int cc  = c & 255;
        int zp  = zps[row];
        const ::int4* p = (const ::int4*)(pw + (size_t)row * (IN_F / 2) + cc * 8);
        ::int4 v0 = p[0], v1 = p[1];
        int pv[8] = {v0.x, v0.y, v0.z, v0.w, v1.x, v1.y, v1.z, v1.w};
        PackI o;
#pragma unroll
        for (int j = 0; j < 8; ++j) {
            o.c[2 * j]     = (char)((pv[j] & 15) - zp);
            o.c[2 * j + 1] = (char)(((pv[j] >> 4) & 15) - zp);
        }
        ((::int4*)wq)[c] = o.v;
    }
}

// ---------- staging helpers (byte-identical to R8/R9, proven) ----------
// LDS half-tile: [128 rows][64 B]; slot s of row R holds chunk s ^ ((R>>1)&3)
// (conflict-free). gload_lds writes linearly; pre-swizzled source chunk
// (l&3) ^ ((l>>3)&3).
// Row semantics (from the staging interleave): A half-tile h, row R <-> global
// row (R>>6)*128 + h*64 + (R&63); B half-tile h, row R <-> global col
// (R>>5)*64 + h*32 + (R&31).
__device__ inline void stA(char* smem, const uint4* gA, int t, int h, int buf, int wo) {
    GLOAD_LDS16(gA + (size_t)h * 64 * KC + (t & (KT - 1)) * 4,
                smem + ((buf * 2 + 0) * 2 + h) * HTB + wo);
}
__device__ inline void stB(char* smem, const uint4* gB, int t, int h, int buf, int wo) {
    GLOAD_LDS16(gB + (size_t)h * 32 * KC + (t & (KT - 1)) * 4,
                smem + ((buf * 2 + 1) * 2 + h) * HTB + wo);
}

// ---------- 32x32x32 fragment reads ----------
// A frag a[mi2][ks] for m-tile mi = 2H+mi2: lane holds A[row = l&31]
// [k = ks*32 + (l>>5)*16 .. +15]; LDS row R = wm*64 + mi2*32 + (l&31) in
// half-tile H (since h = mi>>1). Slot = (ks*2 + (l>>5)) ^ ((R>>1)&3).
// Bank check: over 8 consecutive R, (4R + slot) mod 8 covers all 8 groups ->
// even spread, conflict-free (same involution as staging).
template <int H>
__device__ inline void read_A32(const char* smem, int buf, int wm, int lane,
                                int32x4 (&a)[2][2]) {
    const char* base = smem + ((buf * 2 + 0) * 2 + H) * HTB;
    const int r32 = lane & 31, kh = lane >> 5;
#pragma unroll
    for (int mi2 = 0; mi2 < 2; ++mi2) {
        int R = wm * 64 + mi2 * 32 + r32;
#pragma unroll
        for (int ks = 0; ks < 2; ++ks) {
            int slot = (ks * 2 + kh) ^ ((R >> 1) & 3);
            a[mi2][ks] = *(const int32x4*)(base + R * 64 + slot * 16);
        }
    }
}

// B frag b[nj][ks] for n-tile nj: global col = wn*64 + nj*32 + (l&31) ->
// half-tile nj, row R = wn*32 + (l&31).
__device__ inline void read_B32(const char* smem, int buf, int wn, int lane,
                                int32x4 (&b)[2][2]) {
    const int r32 = lane & 31, kh = lane >> 5;
#pragma unroll
    for (int nj = 0; nj < 2; ++nj) {
        const char* base = smem + ((buf * 2 + 1) * 2 + nj) * HTB;
        int R = wn * 32 + r32;
#pragma unroll
        for (int ks = 0; ks < 2; ++ks) {
            int slot = (ks * 2 + kh) ^ ((R >> 1) & 3);
            b[nj][ks] = *(const int32x4*)(base + R * 64 + slot * 16);
        }
    }
}

// 8 MFMA 32x32x32: one A-half (2 m-tiles) x both n-tiles x 2 k-slices
template <int QM>
__device__ inline void mfma8q(int32x4 (&a)[2][2], int32x4 (&b)[2][2],
                              int32x16 (&acc)[4][2]) {
    __builtin_amdgcn_s_setprio(1);
#pragma unroll
    for (int ks = 0; ks < 2; ++ks)
#pragma unroll
        for (int mi2 = 0; mi2 < 2; ++mi2)
#pragma unroll
            for (int nj = 0; nj < 2; ++nj)
                acc[QM * 2 + mi2][nj] = __builtin_amdgcn_mfma_i32_32x32x32_i8(
                    a[mi2][ks], b[nj][ks], acc[QM * 2 + mi2][nj], 0, 0, 0);
    __builtin_amdgcn_s_setprio(0);
}

// ---------- the 4-phase 256x256 i8 GEMM, 32x32x32 shape ----------
// Schedule/stages/gates byte-identical to R9 (proven): per iter
// Ph1 {read A-half0+B of buf0, stage odd.A1, 8 MFMA}
// Ph2 {read A-half1 of buf0, stage t2.{A0,B0,B1}, GATE buf1 VMW(3), 8 MFMA}
// Ph3/Ph4 symmetric on buf1.
__global__ __launch_bounds__(512, 2) void w4a16_gemm_i8(
    const uint4* __restrict__ xq4, const uint4* __restrict__ wq4,
    const float* __restrict__ srow, const float* __restrict__ scales,
    const float* __restrict__ bias, float* __restrict__ out) {

    extern __shared__ __align__(16) char smem[];   // 64 KiB

    const int tid  = threadIdx.x;
    const int lane = tid & 63;
    const int wid  = tid >> 6;     // 0..7
    const int wm   = wid >> 2;     // 0..1
    const int wn   = wid & 3;      // 0..3

    // 2-D supertile mapping: XCD (bid&7) owns m-tile rows [4*xcd, 4*xcd+4).
    const int bid = blockIdx.x;
    const int xcd = bid & 7;
    const int p   = bid >> 3;          // 0..171
    int tm, tn;
    if (p < 160) { int c = p >> 4, q = p & 15; tm = xcd * 4 + (q & 3); tn = c * 4 + (q >> 2); }
    else         { int q = p - 160;            tm = xcd * 4 + (q & 3); tn = 40 + (q >> 2); }
    const int bm0 = tm * BM;
    const int bn0 = tn * BN;

    // per-thread pre-swizzled staging bases
    const int l2  = lane >> 2;
    const int csw = (lane & 3) ^ ((lane >> 3) & 3);
    const uint4* gA = xq4 + (size_t)(bm0 + (wid >> 2) * 128 + (wid & 3) * 16 + l2) * KC + csw;
    const uint4* gB = wq4 + (size_t)(bn0 + (wid >> 1) * 64 + (wid & 1) * 16 + l2) * KC + csw;
    const int wo = wid * 1024;

    int32x16 acc[4][2];
#pragma unroll
    for (int mi = 0; mi < 4; ++mi)
#pragma unroll
        for (int nj = 0; nj < 2; ++nj)
#pragma unroll
            for (int r = 0; r < 16; ++r) acc[mi][nj][r] = 0;

    int32x4 a[2][2];    // current A-half frags [mi2][ks]
    int32x4 b[2][2];    // both n-tiles        [nj][ks]

    // prologue: t0 fully + t1.{A0,B0,B1}; VMW(3) completes t0 (7 outstanding -> 3).
    stA(smem, gA, 0, 0, 0, wo); stB(smem, gB, 0, 0, 0, wo);
    stB(smem, gB, 0, 1, 0, wo); stA(smem, gA, 0, 1, 0, wo);
    stA(smem, gA, 1, 0, 1, wo); stB(smem, gB, 1, 0, 1, wo);
    stB(smem, gB, 1, 1, 1, wo);
    VMW(3); SBAR0(); BAR();

    for (int i = 0; i < KT / 2; ++i) {
        const int to = 2 * i + 1, t2 = 2 * i + 2, t3 = 2 * i + 3;
        // ---- Ph1: A-half0 + B of buf0; stage to.A1->buf1.A1 ----
        read_A32<0>(smem, 0, wm, lane, a);
        read_B32(smem, 0, wn, lane, b);
        stA(smem, gA, to, 1, 1, wo);
        BAR(); mfma8q<0>(a, b, acc); BAR();
        // ---- Ph2: A-half1 of buf0; stage t2.{A0,B0,B1}->buf0; GATE buf1 ----
        read_A32<1>(smem, 0, wm, lane, a);
        stA(smem, gA, t2, 0, 0, wo);
        stB(smem, gB, t2, 0, 0, wo);
        stB(smem, gB, t2, 1, 0, wo);
        VMW(3); SBAR0(); BAR();
        mfma8q<1>(a, b, acc); BAR();
        // ---- Ph3: A-half0 + B of buf1; stage t2.A1->buf0.A1 ----
        read_A32<0>(smem, 1, wm, lane, a);
        read_B32(smem, 1, wn, lane, b);
        stA(smem, gA, t2, 1, 0, wo);
        BAR(); mfma8q<0>(a, b, acc); BAR();
        // ---- Ph4: A-half1 of buf1; stage t3.{A0,B0,B1}->buf1; GATE buf0 ----
        read_A32<1>(smem, 1, wm, lane, a);
        stA(smem, gA, t3, 0, 1, wo);
        stB(smem, gB, t3, 0, 1, wo);
        stB(smem, gB, t3, 1, 1, wo);
        VMW(3); SBAR0(); BAR();
        mfma8q<1>(a, b, acc); BAR();
    }
    VMW(0);   // drain wrapped trailing stages before LDS may be reused

    // ---- epilogue: 32x32 C/D layout (m74/m101-verified):
    // col = lane&31, row = (reg&3) + 8*(reg>>2) + 4*(lane>>5) ----
#pragma unroll
    for (int mi = 0; mi < 4; ++mi) {
        int rowb = bm0 + wm * 128 + mi * 32 + 4 * (lane >> 5);
#pragma unroll
        for (int nj = 0; nj < 2; ++nj) {
            int col  = bn0 + wn * 64 + nj * 32 + (lane & 31);
            float sc = scales[col];
            float bv = bias[col];
#pragma unroll
            for (int r = 0; r < 16; ++r) {
                int row = rowb + (r & 3) + 8 * (r >> 2);
                __builtin_nontemporal_store(
                    (float)acc[mi][nj][r] * (srow[row] * sc) + bv,
                    &out[(size_t)row * OUT_F + col]);
            }
        }
    }
}

// ---------- fallback (ws too small): reg-staged bf16 128^2 with inline dequant ----------
#define FBM 128
#define FBN 128
#define FTM (M_DIM / FBM)
#define FTN (OUT_F / FBN)
#define FNWG (FTM * FTN)

__global__ __launch_bounds__(256) void w4a16_gemm_fb(
    const float* __restrict__ xf,
    const int* __restrict__ pw,
    const float* __restrict__ scales, const int* __restrict__ zps,
    const float* __restrict__ bias, float* __restrict__ out) {

    __shared__ __align__(16) __bf16 As[FBM * 64];
    __shared__ __align__(16) __bf16 Bs[FBN * 64];

    const int tid  = threadIdx.x;
    const int lane = tid & 63;
    const int wid  = tid >> 6;
    const int wm   = wid >> 1;
    const int wn   = wid & 1;

    int orig = blockIdx.x;
    int wg   = (orig & 7) * (FNWG / 8) + (orig >> 3);
    const int bm0 = (wg / FTN) * FBM;
    const int bn0 = (wg % FTN) * FBN;

    f32x4 acc[4][4];
#pragma unroll
    for (int i = 0; i < 4; ++i)
#pragma unroll
        for (int j = 0; j < 4; ++j) acc[i][j] = {0.f, 0.f, 0.f, 0.f};

    for (int kt = 0; kt < IN_F / 64; ++kt) {
#pragma unroll
        for (int i = 0; i < 4; ++i) {
            int ci  = i * 256 + tid;
            int row = ci >> 3, c8 = ci & 7;
            const float4* pp = (const float4*)(xf + (size_t)(bm0 + row) * IN_F + kt * 64 + c8 * 8);
            uint4 d = pack8_f(pp[0], pp[1]);
            *(uint4*)((char*)As + row * 128 + ((c8 * 16) ^ ((row & 7) << 4))) = d;
        }
#pragma unroll
        for (int i = 0; i < 4; ++i) {
            int ci  = i * 256 + tid;
            int row = ci >> 3, c8 = ci & 7;
            int r    = bn0 + row;
            float s  = scales[r];
            float zb = -s * (float)zps[r];
            int4 v = *(const int4*)(pw + (size_t)r * (IN_F / 2) + kt * 32 + c8 * 4);
            uint4 d = dequant8(v, s, zb);
            *(uint4*)((char*)Bs + row * 128 + ((c8 * 16) ^ ((row & 7) << 4))) = d;
        }
        __syncthreads();

#pragma unroll
        for (int kk = 0; kk < 2; ++kk) {
            short8 a[4], b[4];
#pragma unroll
            for (int mi = 0; mi < 4; ++mi) {
                int row = wm * 64 + mi * 16 + (lane & 15);
                a[mi] = *(const short8*)((const char*)As + row * 128 +
                                         ((kk * 64 + (lane >> 4) * 16) ^ ((row & 7) << 4)));
            }
#pragma unroll
            for (int ni = 0; ni < 4; ++ni) {
                int row = wn * 64 + ni * 16 + (lane & 15);
                b[ni] = *(const short8*)((const char*)Bs + row * 128 +
                                         ((kk * 64 + (lane >> 4) * 16) ^ ((row & 7) << 4)));
            }
#pragma unroll
            for (int mi = 0; mi < 4; ++mi)
#pragma unroll
                for (int ni = 0; ni < 4; ++ni)
                    acc[mi][ni] = __builtin_amdgcn_mfma_f32_16x16x32_bf16(a[mi], b[ni], acc[mi][ni], 0, 0, 0);
        }
        __syncthreads();
    }

#pragma unroll
    for (int ni = 0; ni < 4; ++ni) {
        int col  = bn0 + wn * 64 + ni * 16 + (lane & 15);
        float bv = bias[col];
#pragma unroll
        for (int mi = 0; mi < 4; ++mi) {
            int row0 = bm0 + wm * 64 + mi * 16 + (lane >> 4) * 4;
#pragma unroll
            for (int r = 0; r < 4; ++r)
                out[(size_t)(row0 + r) * OUT_F + col] = acc[mi][ni][r] + bv;
        }
    }
}

extern "C" void kernel_launch(void* const* d_in, const int* in_sizes, int n_in,
                              void* d_out, int out_size, void* d_ws, size_t ws_size,
                              hipStream_t stream) {
    const float* x      = (const float*)d_in[0];
    const int* pw       = (const int*)d_in[1];
    const float* scales = (const float*)d_in[2];
    const int* zps      = (const int*)d_in[3];
    const float* bias   = (const float*)d_in[4];
    float* out          = (float*)d_out;

    const size_t xq_bytes = (size_t)M_DIM * IN_F;        // 32 MiB i8
    const size_t sr_bytes = 65536;                       // srow f32 + pad
    const size_t wq_bytes = (size_t)OUT_F * IN_F;        // ~43 MiB i8
    const bool predeq = ws_size >= xq_bytes + sr_bytes + wq_bytes;

    if (predeq) {
        char*  xq   = (char*)d_ws;
        float* srow = (float*)((char*)d_ws + xq_bytes);
        char*  wq   = (char*)d_ws + xq_bytes + sr_bytes;
        quant_x_kernel<<<dim3(M_DIM), dim3(256), 0, stream>>>(x, xq, srow);
        deqw_i8_kernel<<<dim3(2048), dim3(256), 0, stream>>>(pw, zps, wq, OUT_F * (IN_F / 16));
        (void)hipFuncSetAttribute((const void*)w4a16_gemm_i8,
                                  hipFuncAttributeMaxDynamicSharedMemorySize, 65536);
        w4a16_gemm_i8<<<dim3(NWG), dim3(512), 65536, stream>>>(
            (const uint4*)xq, (const uint4*)wq, srow, scales, bias, out);
    } else {
        w4a16_gemm_fb<<<dim3(FNWG), dim3(256), 0, stream>>>(x, pw, scales, zps, bias, out);
    }
}

// Round 12
// 441.969 us; speedup vs baseline: 1.0391x; 1.0391x over previous
//
#include <hip/hip_runtime.h>
#include <hip/hip_bf16.h>
#include <stdint.h>

#define IN_F   4096
#define OUT_F  11008
#define M_DIM  8192          // B*S

// ---------------- 256x128 geometry, int8, triple-buffered single-phase ----------------
#define BM 256
#define BN 128
#define TM (M_DIM / BM)        // 32
#define TN (OUT_F / BN)        // 86
#define NWG (TM * TN)          // 2752 = 8 * 344 -> 10.75 rounds (2.3% tail)
#define KT (IN_F / 64)         // 64 K-tiles of 64 i8
#define KC (IN_F / 16)         // 256 16-B chunks per row
#define TILE_B 24576           // per-buffer: A 16 KB + B 8 KB
#define B_OFF  16384

typedef __attribute__((ext_vector_type(4))) int   int32x4;
typedef __attribute__((ext_vector_type(8))) short short8;
typedef __attribute__((ext_vector_type(4))) float f32x4;

union Pack8 { __bf16 h[8]; uint4 u; };
union PackI { char c[16]; ::int4 v; };

__device__ inline uint4 pack8_f(float4 f0, float4 f1) {
    Pack8 o;
    o.h[0] = (__bf16)f0.x; o.h[1] = (__bf16)f0.y;
    o.h[2] = (__bf16)f0.z; o.h[3] = (__bf16)f0.w;
    o.h[4] = (__bf16)f1.x; o.h[5] = (__bf16)f1.y;
    o.h[6] = (__bf16)f1.z; o.h[7] = (__bf16)f1.w;
    return o.u;
}

__device__ inline uint4 dequant8(int4 v, float s, float zb) {
    Pack8 o;
    int pv[4] = {v.x, v.y, v.z, v.w};
#pragma unroll
    for (int j = 0; j < 4; ++j) {
        o.h[2 * j]     = (__bf16)fmaf((float)(pv[j] & 15), s, zb);
        o.h[2 * j + 1] = (__bf16)fmaf((float)((pv[j] >> 4) & 15), s, zb);
    }
    return o.u;
}

#define GLOAD_LDS16(g, l)                                                     \
    __builtin_amdgcn_global_load_lds(                                         \
        (const __attribute__((address_space(1))) void*)(g),                   \
        (__attribute__((address_space(3))) void*)(l), 16, 0, 0)

#define BAR()   __builtin_amdgcn_s_barrier()
#define SBAR0() __builtin_amdgcn_sched_barrier(0)
#define VMW(n)  asm volatile("s_waitcnt vmcnt(" #n ")" ::: "memory")

// ---------- preprocessing: x fp32 -> i8 with per-row absmax scale (proven) ----------
__global__ __launch_bounds__(256) void quant_x_kernel(const float* __restrict__ x,
        char* __restrict__ xq, float* __restrict__ srow) {
    const int row = blockIdx.x;
    const int t   = threadIdx.x;
    const float4* xr = (const float4*)(x + (size_t)row * IN_F) + t * 4;
    float4 v[4];
    float am = 0.f;
#pragma unroll
    for (int j = 0; j < 4; ++j) {
        v[j] = xr[j];
        am = fmaxf(am, fmaxf(fmaxf(fabsf(v[j].x), fabsf(v[j].y)),
                             fmaxf(fabsf(v[j].z), fabsf(v[j].w))));
    }
#pragma unroll
    for (int off = 32; off; off >>= 1) am = fmaxf(am, __shfl_xor(am, off, 64));
    __shared__ float wm4[4];
    if ((t & 63) == 0) wm4[t >> 6] = am;
    __syncthreads();
    am = fmaxf(fmaxf(wm4[0], wm4[1]), fmaxf(wm4[2], wm4[3]));
    const float qs = am > 0.f ? 127.f / am : 0.f;
    if (t == 0) srow[row] = am > 0.f ? am * (1.f / 127.f) : 0.f;
    PackI o;
#pragma unroll
    for (int j = 0; j < 4; ++j) {
        const float* f = (const float*)&v[j];
#pragma unroll
        for (int e = 0; e < 4; ++e) {
            float q = rintf(f[e] * qs);
            q = fminf(127.f, fmaxf(-127.f, q));
            o.c[j * 4 + e] = (char)(int)q;
        }
    }
    ((::int4*)(xq + (size_t)row * IN_F))[t] = o.v;
}

// ---------- preprocessing: packed int4 W -> i8 (q - zp, EXACT, proven) ----------
__global__ void deqw_i8_kernel(const int* __restrict__ pw, const int* __restrict__ zps,
                               char* __restrict__ wq, int nChunks) {
    int stride = gridDim.x * blockDim.x;
    for (int c = blockIdx.x * blockDim.x + threadIdx.x; c < nChunks; c += stride) {
        int row = c >> 8;          // 256 16-B chunks per row
        int cc  = c & 255;
        int zp  = zps[row];
        const ::int4* p = (const ::int4*)(pw + (size_t)row * (IN_F / 2) + cc * 8);
        ::int4 v0 = p[0], v1 = p[1];
        int pv[8] = {v0.x, v0.y, v0.z, v0.w, v1.x, v1.y, v1.z, v1.w};
        PackI o;
#pragma unroll
        for (int j = 0; j < 8; ++j) {
            o.c[2 * j]     = (char)((pv[j] & 15) - zp);
            o.c[2 * j + 1] = (char)(((pv[j] >> 4) & 15) - zp);
        }
        ((::int4*)wq)[c] = o.v;
    }
}

// ---------- the triple-buffered 256x128 i8 GEMM ----------
// LDS per buffer (24 KB): A rows 0..255 x 64 B at [0,16K) linear; B rows (output
// cols) 0..127 x 64 B at [16K,24K). Slot swizzle (R8-proven, 64-B rows): slot s
// of row r holds chunk s ^ ((r>>1)&3); staging source pre-swizzle (l&3)^((l>>3)&3)
// (row per lane = base + l>>2 with 16-row-aligned wave bases -> (r>>1)&3 = (l>>3)&3).
// K-loop (single phase per K-tile): stage tile kt+2 -> bufS (3 gloads/thread);
// VMW(6) completes tile kt collectively (outstanding 9 -> 6, FIFO: kt,kt+1,kt+2
// x3 loads); BAR makes drain collective; reads + 16 MFMA with NO intervening
// barrier (waves on a SIMD self-stagger read vs MFMA); end-BAR = WAR fence for
// next iter's overwrite of bufR (reused at kt+1... rotation puts bufR back as
// stage target after 2 iters; nearest hazard is 1 barrier away - safe since all
// reads retire before the end-BAR via compiler lgkm waits feeding the MFMAs).
__global__ __launch_bounds__(512, 2) void w4a16_gemm_i8(
    const uint4* __restrict__ xq4, const uint4* __restrict__ wq4,
    const float* __restrict__ srow, const float* __restrict__ scales,
    const float* __restrict__ bias, float* __restrict__ out) {

    extern __shared__ __align__(16) char smem[];   // 72 KiB (3 buffers)

    const int tid  = threadIdx.x;
    const int lane = tid & 63;
    const int wid  = tid >> 6;     // 0..7
    const int wm   = wid >> 1;     // 0..3 (m-group, 64 rows each)
    const int wn   = wid & 1;      // 0..1 (n-group, 64 cols each)

    // 2-D supertile: XCD (bid&7) owns tm in [4*xcd, 4*xcd+4); walk 4x4 supertiles
    // across TN=86 (21 full col-groups + ragged 2). Bijective: 8*(336+8)=2752.
    const int bid = blockIdx.x;
    const int xcd = bid & 7;
    const int p   = bid >> 3;          // 0..343
    int tm, tn;
    if (p < 336) { int c = p >> 4, q = p & 15; tm = xcd * 4 + (q & 3); tn = c * 4 + (q >> 2); }
    else         { int q = p - 336;            tm = xcd * 4 + (q & 3); tn = 84 + (q >> 2); }
    const int bm0 = tm * BM;
    const int bn0 = tn * BN;

    // staging bases: lane l covers row base + (l>>2), slot l&3, source chunk csw
    const int r4  = (wid << 4) + (lane >> 2);          // 0..127
    const int csw = (lane & 3) ^ ((lane >> 3) & 3);
    const uint4* gA  = xq4 + (size_t)(bm0 + r4) * KC + csw;
    const uint4* gA2 = gA + (size_t)128 * KC;
    const uint4* gB  = wq4 + (size_t)(bn0 + r4) * KC + csw;
    const int wo = wid << 10;                          // wid*1024

    int32x4 acc[4][4];
#pragma unroll
    for (int mi = 0; mi < 4; ++mi)
#pragma unroll
        for (int nj = 0; nj < 4; ++nj) acc[mi][nj] = {0, 0, 0, 0};

    // prologue: tiles 0,1 -> bufs 0,1 (6 loads)
#pragma unroll
    for (int t = 0; t < 2; ++t) {
        int off = t * TILE_B + wo;
        GLOAD_LDS16(gA + t * 4, smem + off);
        GLOAD_LDS16(gA2 + t * 4, smem + off + 8192);
        GLOAD_LDS16(gB + t * 4, smem + t * TILE_B + B_OFF + wo);
    }

    int bR = 0, bS = 2;   // read buffer, stage buffer (middle implied)
    for (int kt = 0; kt < KT; ++kt) {
        // stage tile kt+2 (masked wrap; trailing wrapped stages never read)
        const int tc = ((kt + 2) & (KT - 1)) * 4;
        {
            int off = bS * TILE_B + wo;
            GLOAD_LDS16(gA + tc, smem + off);
            GLOAD_LDS16(gA2 + tc, smem + off + 8192);
            GLOAD_LDS16(gB + tc, smem + bS * TILE_B + B_OFF + wo);
        }
        VMW(6); SBAR0(); BAR(); SBAR0();   // tile kt fully in bufR, collectively

        const char* base = smem + bR * TILE_B;
        int32x4 a[4], b[4];
#pragma unroll
        for (int mi = 0; mi < 4; ++mi) {
            int row = wm * 64 + mi * 16 + (lane & 15);
            a[mi] = *(const int32x4*)(base + row * 64 +
                     (((lane >> 4) * 16) ^ (((row >> 1) & 3) << 4)));
        }
#pragma unroll
        for (int nj = 0; nj < 4; ++nj) {
            int row = wn * 64 + nj * 16 + (lane & 15);
            b[nj] = *(const int32x4*)(base + B_OFF + row * 64 +
                     (((lane >> 4) * 16) ^ (((row >> 1) & 3) << 4)));
        }
        __builtin_amdgcn_s_setprio(1);
#pragma unroll
        for (int mi = 0; mi < 4; ++mi)
#pragma unroll
            for (int nj = 0; nj < 4; ++nj)
                acc[mi][nj] = __builtin_amdgcn_mfma_i32_16x16x64_i8(
                    a[mi], b[nj], acc[mi][nj], 0, 0, 0);
        __builtin_amdgcn_s_setprio(0);
        BAR();                              // WAR fence before bufR is re-staged

        int t = bR; bR = (bR == 2) ? 0 : bR + 1; bS = (bS == 2) ? 0 : bS + 1; (void)t;
    }
    VMW(0);   // drain wrapped trailing stages before endpgm

    // ---- epilogue: out = i32_acc * srow[row] * scales[col] + bias[col] ----
    // C/D 16x16 layout (proven): col = lane&15, row = (lane>>4)*4 + rr
#pragma unroll
    for (int mi = 0; mi < 4; ++mi) {
        int row0 = bm0 + wm * 64 + mi * 16 + (lane >> 4) * 4;
        float sr[4];
#pragma unroll
        for (int rr = 0; rr < 4; ++rr) sr[rr] = srow[row0 + rr];
#pragma unroll
        for (int nj = 0; nj < 4; ++nj) {
            int col  = bn0 + wn * 64 + nj * 16 + (lane & 15);
            float sc = scales[col];
            float bv = bias[col];
#pragma unroll
            for (int rr = 0; rr < 4; ++rr)
                __builtin_nontemporal_store(
                    (float)acc[mi][nj][rr] * (sr[rr] * sc) + bv,
                    &out[(size_t)(row0 + rr) * OUT_F + col]);
        }
    }
}

// ---------- fallback (ws too small): reg-staged bf16 128^2 with inline dequant ----------
#define FBM 128
#define FBN 128
#define FTM (M_DIM / FBM)
#define FTN (OUT_F / FBN)
#define FNWG (FTM * FTN)

__global__ __launch_bounds__(256) void w4a16_gemm_fb(
    const float* __restrict__ xf,
    const int* __restrict__ pw,
    const float* __restrict__ scales, const int* __restrict__ zps,
    const float* __restrict__ bias, float* __restrict__ out) {

    __shared__ __align__(16) __bf16 As[FBM * 64];
    __shared__ __align__(16) __bf16 Bs[FBN * 64];

    const int tid  = threadIdx.x;
    const int lane = tid & 63;
    const int wid  = tid >> 6;
    const int wm   = wid >> 1;
    const int wn   = wid & 1;

    int orig = blockIdx.x;
    int wg   = (orig & 7) * (FNWG / 8) + (orig >> 3);
    const int bm0 = (wg / FTN) * FBM;
    const int bn0 = (wg % FTN) * FBN;

    f32x4 acc[4][4];
#pragma unroll
    for (int i = 0; i < 4; ++i)
#pragma unroll
        for (int j = 0; j < 4; ++j) acc[i][j] = {0.f, 0.f, 0.f, 0.f};

    for (int kt = 0; kt < IN_F / 64; ++kt) {
#pragma unroll
        for (int i = 0; i < 4; ++i) {
            int ci  = i * 256 + tid;
            int row = ci >> 3, c8 = ci & 7;
            const float4* pp = (const float4*)(xf + (size_t)(bm0 + row) * IN_F + kt * 64 + c8 * 8);
            uint4 d = pack8_f(pp[0], pp[1]);
            *(uint4*)((char*)As + row * 128 + ((c8 * 16) ^ ((row & 7) << 4))) = d;
        }
#pragma unroll
        for (int i = 0; i < 4; ++i) {
            int ci  = i * 256 + tid;
            int row = ci >> 3, c8 = ci & 7;
            int r    = bn0 + row;
            float s  = scales[r];
            float zb = -s * (float)zps[r];
            int4 v = *(const int4*)(pw + (size_t)r * (IN_F / 2) + kt * 32 + c8 * 4);
            uint4 d = dequant8(v, s, zb);
            *(uint4*)((char*)Bs + row * 128 + ((c8 * 16) ^ ((row & 7) << 4))) = d;
        }
        __syncthreads();

#pragma unroll
        for (int kk = 0; kk < 2; ++kk) {
            short8 a[4], b[4];
#pragma unroll
            for (int mi = 0; mi < 4; ++mi) {
                int row = wm * 64 + mi * 16 + (lane & 15);
                a[mi] = *(const short8*)((const char*)As + row * 128 +
                                         ((kk * 64 + (lane >> 4) * 16) ^ ((row & 7) << 4)));
            }
#pragma unroll
            for (int ni = 0; ni < 4; ++ni) {
                int row = wn * 64 + ni * 16 + (lane & 15);
                b[ni] = *(const short8*)((const char*)Bs + row * 128 +
                                         ((kk * 64 + (lane >> 4) * 16) ^ ((row & 7) << 4)));
            }
#pragma unroll
            for (int mi = 0; mi < 4; ++mi)
#pragma unroll
                for (int ni = 0; ni < 4; ++ni)
                    acc[mi][ni] = __builtin_amdgcn_mfma_f32_16x16x32_bf16(a[mi], b[ni], acc[mi][ni], 0, 0, 0);
        }
        __syncthreads();
    }

#pragma unroll
    for (int ni = 0; ni < 4; ++ni) {
        int col  = bn0 + wn * 64 + ni * 16 + (lane & 15);
        float bv = bias[col];
#pragma unroll
        for (int mi = 0; mi < 4; ++mi) {
            int row0 = bm0 + wm * 64 + mi * 16 + (lane >> 4) * 4;
#pragma unroll
            for (int r = 0; r < 4; ++r)
                out[(size_t)(row0 + r) * OUT_F + col] = acc[mi][ni][r] + bv;
        }
    }
}

extern "C" void kernel_launch(void* const* d_in, const int* in_sizes, int n_in,
                              void* d_out, int out_size, void* d_ws, size_t ws_size,
                              hipStream_t stream) {
    const float* x      = (const float*)d_in[0];
    const int* pw       = (const int*)d_in[1];
    const float* scales = (const float*)d_in[2];
    const int* zps      = (const int*)d_in[3];
    const float* bias   = (const float*)d_in[4];
    float* out          = (float*)d_out;

    const size_t xq_bytes = (size_t)M_DIM * IN_F;        // 32 MiB i8
    const size_t sr_bytes = 65536;                       // srow f32 + pad
    const size_t wq_bytes = (size_t)OUT_F * IN_F;        // ~43 MiB i8
    const bool predeq = ws_size >= xq_bytes + sr_bytes + wq_bytes;

    if (predeq) {
        char*  xq   = (char*)d_ws;
        float* srow = (float*)((char*)d_ws + xq_bytes);
        char*  wq   = (char*)d_ws + xq_bytes + sr_bytes;
        quant_x_kernel<<<dim3(M_DIM), dim3(256), 0, stream>>>(x, xq, srow);
        deqw_i8_kernel<<<dim3(2048), dim3(256), 0, stream>>>(pw, zps, wq, OUT_F * (IN_F / 16));
        (void)hipFuncSetAttribute((const void*)w4a16_gemm_i8,
                                  hipFuncAttributeMaxDynamicSharedMemorySize, 3 * TILE_B);
        w4a16_gemm_i8<<<dim3(NWG), dim3(512), 3 * TILE_B, stream>>>(
            (const uint4*)xq, (const uint4*)wq, srow, scales, bias, out);
    } else {
        w4a16_gemm_fb<<<dim3(FNWG), dim3(256), 0, stream>>>(x, pw, scales, zps, bias, out);
    }
}

// Round 13
// 435.945 us; speedup vs baseline: 1.0535x; 1.0138x over previous
//
#include <hip/hip_runtime.h>
#include <hip/hip_bf16.h>
#include <stdint.h>

#define IN_F   4096
#define OUT_F  11008
#define M_DIM  8192          // B*S

// ------- 256x128 block, 4 waves of 128x64, int8, triple-buffered single-phase -------
#define BM 256
#define BN 128
#define TM (M_DIM / BM)        // 32
#define TN (OUT_F / BN)        // 86
#define NWG (TM * TN)          // 2752 -> 10.75 rounds (2.3% tail)
#define KT (IN_F / 64)         // 64 K-tiles of 64 i8
#define KC (IN_F / 16)         // 256 16-B chunks per row
#define TILE_B 24576           // per-buffer: A 16 KB + B 8 KB
#define B_OFF  16384

typedef __attribute__((ext_vector_type(4))) int   int32x4;
typedef __attribute__((ext_vector_type(8))) short short8;
typedef __attribute__((ext_vector_type(4))) float f32x4;

union Pack8 { __bf16 h[8]; uint4 u; };
union PackI { char c[16]; ::int4 v; };

__device__ inline uint4 pack8_f(float4 f0, float4 f1) {
    Pack8 o;
    o.h[0] = (__bf16)f0.x; o.h[1] = (__bf16)f0.y;
    o.h[2] = (__bf16)f0.z; o.h[3] = (__bf16)f0.w;
    o.h[4] = (__bf16)f1.x; o.h[5] = (__bf16)f1.y;
    o.h[6] = (__bf16)f1.z; o.h[7] = (__bf16)f1.w;
    return o.u;
}

__device__ inline uint4 dequant8(int4 v, float s, float zb) {
    Pack8 o;
    int pv[4] = {v.x, v.y, v.z, v.w};
#pragma unroll
    for (int j = 0; j < 4; ++j) {
        o.h[2 * j]     = (__bf16)fmaf((float)(pv[j] & 15), s, zb);
        o.h[2 * j + 1] = (__bf16)fmaf((float)((pv[j] >> 4) & 15), s, zb);
    }
    return o.u;
}

#define GLOAD_LDS16(g, l)                                                     \
    __builtin_amdgcn_global_load_lds(                                         \
        (const __attribute__((address_space(1))) void*)(g),                   \
        (__attribute__((address_space(3))) void*)(l), 16, 0, 0)

#define BAR()   __builtin_amdgcn_s_barrier()
#define SBAR0() __builtin_amdgcn_sched_barrier(0)
#define VMW(n)  asm volatile("s_waitcnt vmcnt(" #n ")" ::: "memory")

// ---------- preprocessing: x fp32 -> i8 with per-row absmax scale (proven) ----------
__global__ __launch_bounds__(256) void quant_x_kernel(const float* __restrict__ x,
        char* __restrict__ xq, float* __restrict__ srow) {
    const int row = blockIdx.x;
    const int t   = threadIdx.x;
    const float4* xr = (const float4*)(x + (size_t)row * IN_F) + t * 4;
    float4 v[4];
    float am = 0.f;
#pragma unroll
    for (int j = 0; j < 4; ++j) {
        v[j] = xr[j];
        am = fmaxf(am, fmaxf(fmaxf(fabsf(v[j].x), fabsf(v[j].y)),
                             fmaxf(fabsf(v[j].z), fabsf(v[j].w))));
    }
#pragma unroll
    for (int off = 32; off; off >>= 1) am = fmaxf(am, __shfl_xor(am, off, 64));
    __shared__ float wm4[4];
    if ((t & 63) == 0) wm4[t >> 6] = am;
    __syncthreads();
    am = fmaxf(fmaxf(wm4[0], wm4[1]), fmaxf(wm4[2], wm4[3]));
    const float qs = am > 0.f ? 127.f / am : 0.f;
    if (t == 0) srow[row] = am > 0.f ? am * (1.f / 127.f) : 0.f;
    PackI o;
#pragma unroll
    for (int j = 0; j < 4; ++j) {
        const float* f = (const float*)&v[j];
#pragma unroll
        for (int e = 0; e < 4; ++e) {
            float q = rintf(f[e] * qs);
            q = fminf(127.f, fmaxf(-127.f, q));
            o.c[j * 4 + e] = (char)(int)q;
        }
    }
    ((::int4*)(xq + (size_t)row * IN_F))[t] = o.v;
}

// ---------- preprocessing: packed int4 W -> i8 (q - zp, EXACT, proven) ----------
__global__ void deqw_i8_kernel(const int* __restrict__ pw, const int* __restrict__ zps,
                               char* __restrict__ wq, int nChunks) {
    int stride = gridDim.x * blockDim.x;
    for (int c = blockIdx.x * blockDim.x + threadIdx.x; c < nChunks; c += stride) {
        int row = c >> 8;          // 256 16-B chunks per row
        int cc  = c & 255;
        int zp  = zps[row];
        const ::int4* p = (const ::int4*)(pw + (size_t)row * (IN_F / 2) + cc * 8);
        ::int4 v0 = p[0], v1 = p[1];
        int pv[8] = {v0.x, v0.y, v0.z, v0.w, v1.x, v1.y, v1.z, v1.w};
        PackI o;
#pragma unroll
        for (int j = 0; j < 8; ++j) {
            o.c[2 * j]     = (char)((pv[j] & 15) - zp);
            o.c[2 * j + 1] = (char)(((pv[j] >> 4) & 15) - zp);
        }
        ((::int4*)wq)[c] = o.v;
    }
}

// ---------- the triple-buffered 256x128 i8 GEMM, 128x64 wave tiles ----------
// LDS per buffer (24 KB): A [256 rows][64 B] at [0,16K); B [128 rows][64 B] at
// [16K,24K). Slot swizzle (R8-proven): slot s of row r holds chunk s^((r>>1)&3);
// staging source pre-swizzle (l&3)^((l>>3)&3) (16-row-aligned issue bases).
// K-loop: stage tile kt+2 -> bufS (6 gloads/thread: A x4, B x2); VMW(12)
// completes tile kt collectively (18 outstanding -> 12); BAR; reads (12 x b128)
// + 32 MFMA (compiler-interleaved); end-BAR = WAR fence (bufS(k) = bufR(k-1),
// all k-1 reads retired before any wave passed iter-k's... the end-BAR of k-1).
__global__ __launch_bounds__(256, 2) void w4a16_gemm_i8(
    const uint4* __restrict__ xq4, const uint4* __restrict__ wq4,
    const float* __restrict__ srow, const float* __restrict__ scales,
    const float* __restrict__ bias, float* __restrict__ out) {

    extern __shared__ __align__(16) char smem[];   // 72 KiB (3 buffers)

    const int tid  = threadIdx.x;
    const int lane = tid & 63;
    const int wid  = tid >> 6;     // 0..3
    const int wm   = wid >> 1;     // 0..1 (m-group, 128 rows)
    const int wn   = wid & 1;      // 0..1 (n-group, 64 cols)

    // 2-D supertile: XCD (bid&7) owns tm in [4*xcd,4*xcd+4); 4x4 supertiles
    // across TN=86 (21 full col-groups + ragged 2). Bijective (R12-proven).
    const int bid = blockIdx.x;
    const int xcd = bid & 7;
    const int p   = bid >> 3;          // 0..343
    int tm, tn;
    if (p < 336) { int c = p >> 4, q = p & 15; tm = xcd * 4 + (q & 3); tn = c * 4 + (q >> 2); }
    else         { int q = p - 336;            tm = xcd * 4 + (q & 3); tn = 84 + (q >> 2); }
    const int bm0 = tm * BM;
    const int bn0 = tn * BN;

    // staging: issue i covers rows i*64 + wid*16 + (lane>>2), slot lane&3,
    // source chunk csw; LDS dest = bufbase + i*4096 + wid*1024 (+ lane*16 implicit)
    const int r4  = (wid << 4) + (lane >> 2);          // 0..63
    const int csw = (lane & 3) ^ ((lane >> 3) & 3);
    const uint4* gA = xq4 + (size_t)(bm0 + r4) * KC + csw;
    const uint4* gB = wq4 + (size_t)(bn0 + r4) * KC + csw;
    const int wo = wid << 10;

    int32x4 acc[8][4];
#pragma unroll
    for (int mi = 0; mi < 8; ++mi)
#pragma unroll
        for (int nj = 0; nj < 4; ++nj) acc[mi][nj] = {0, 0, 0, 0};

    // prologue: tiles 0,1 -> bufs 0,1 (12 loads)
#pragma unroll
    for (int t = 0; t < 2; ++t) {
        char* bb = smem + t * TILE_B;
#pragma unroll
        for (int i = 0; i < 4; ++i)
            GLOAD_LDS16(gA + (size_t)(i * 64) * KC + t * 4, bb + i * 4096 + wo);
#pragma unroll
        for (int i = 0; i < 2; ++i)
            GLOAD_LDS16(gB + (size_t)(i * 64) * KC + t * 4, bb + B_OFF + i * 4096 + wo);
    }

    int bR = 0, bS = 2;   // read buffer, stage buffer
    for (int kt = 0; kt < KT; ++kt) {
        // stage tile kt+2 (wrapped trailing stages never read)
        const int tc = ((kt + 2) & (KT - 1)) * 4;
        {
            char* bb = smem + bS * TILE_B;
#pragma unroll
            for (int i = 0; i < 4; ++i)
                GLOAD_LDS16(gA + (size_t)(i * 64) * KC + tc, bb + i * 4096 + wo);
#pragma unroll
            for (int i = 0; i < 2; ++i)
                GLOAD_LDS16(gB + (size_t)(i * 64) * KC + tc, bb + B_OFF + i * 4096 + wo);
        }
        VMW(12); SBAR0(); BAR(); SBAR0();   // tile kt fully in bufR, collectively

        const char* base = smem + bR * TILE_B;
        int32x4 a[8], b[4];
#pragma unroll
        for (int mi = 0; mi < 8; ++mi) {
            int row = wm * 128 + mi * 16 + (lane & 15);
            a[mi] = *(const int32x4*)(base + row * 64 +
                     (((lane >> 4) * 16) ^ (((row >> 1) & 3) << 4)));
        }
#pragma unroll
        for (int nj = 0; nj < 4; ++nj) {
            int row = wn * 64 + nj * 16 + (lane & 15);
            b[nj] = *(const int32x4*)(base + B_OFF + row * 64 +
                     (((lane >> 4) * 16) ^ (((row >> 1) & 3) << 4)));
        }
        __builtin_amdgcn_s_setprio(1);
#pragma unroll
        for (int mi = 0; mi < 8; ++mi)
#pragma unroll
            for (int nj = 0; nj < 4; ++nj)
                acc[mi][nj] = __builtin_amdgcn_mfma_i32_16x16x64_i8(
                    a[mi], b[nj], acc[mi][nj], 0, 0, 0);
        __builtin_amdgcn_s_setprio(0);
        BAR();                              // WAR fence before bufR is re-staged

        bR = (bR == 2) ? 0 : bR + 1; bS = (bS == 2) ? 0 : bS + 1;
    }
    VMW(0);   // drain wrapped trailing stages before endpgm

    // ---- epilogue: out = i32_acc * srow[row] * scales[col] + bias[col] ----
    // C/D 16x16 layout (proven): col = lane&15, row = (lane>>4)*4 + rr
#pragma unroll
    for (int mi = 0; mi < 8; ++mi) {
        int row0 = bm0 + wm * 128 + mi * 16 + (lane >> 4) * 4;
        float sr[4];
#pragma unroll
        for (int rr = 0; rr < 4; ++rr) sr[rr] = srow[row0 + rr];
#pragma unroll
        for (int nj = 0; nj < 4; ++nj) {
            int col  = bn0 + wn * 64 + nj * 16 + (lane & 15);
            float sc = scales[col];
            float bv = bias[col];
#pragma unroll
            for (int rr = 0; rr < 4; ++rr)
                __builtin_nontemporal_store(
                    (float)acc[mi][nj][rr] * (sr[rr] * sc) + bv,
                    &out[(size_t)(row0 + rr) * OUT_F + col]);
        }
    }
}

// ---------- fallback (ws too small): reg-staged bf16 128^2 with inline dequant ----------
#define FBM 128
#define FBN 128
#define FTM (M_DIM / FBM)
#define FTN (OUT_F / FBN)
#define FNWG (FTM * FTN)

__global__ __launch_bounds__(256) void w4a16_gemm_fb(
    const float* __restrict__ xf,
    const int* __restrict__ pw,
    const float* __restrict__ scales, const int* __restrict__ zps,
    const float* __restrict__ bias, float* __restrict__ out) {

    __shared__ __align__(16) __bf16 As[FBM * 64];
    __shared__ __align__(16) __bf16 Bs[FBN * 64];

    const int tid  = threadIdx.x;
    const int lane = tid & 63;
    const int wid  = tid >> 6;
    const int wm   = wid >> 1;
    const int wn   = wid & 1;

    int orig = blockIdx.x;
    int wg   = (orig & 7) * (FNWG / 8) + (orig >> 3);
    const int bm0 = (wg / FTN) * FBM;
    const int bn0 = (wg % FTN) * FBN;

    f32x4 acc[4][4];
#pragma unroll
    for (int i = 0; i < 4; ++i)
#pragma unroll
        for (int j = 0; j < 4; ++j) acc[i][j] = {0.f, 0.f, 0.f, 0.f};

    for (int kt = 0; kt < IN_F / 64; ++kt) {
#pragma unroll
        for (int i = 0; i < 4; ++i) {
            int ci  = i * 256 + tid;
            int row = ci >> 3, c8 = ci & 7;
            const float4* pp = (const float4*)(xf + (size_t)(bm0 + row) * IN_F + kt * 64 + c8 * 8);
            uint4 d = pack8_f(pp[0], pp[1]);
            *(uint4*)((char*)As + row * 128 + ((c8 * 16) ^ ((row & 7) << 4))) = d;
        }
#pragma unroll
        for (int i = 0; i < 4; ++i) {
            int ci  = i * 256 + tid;
            int row = ci >> 3, c8 = ci & 7;
            int r    = bn0 + row;
            float s  = scales[r];
            float zb = -s * (float)zps[r];
            int4 v = *(const int4*)(pw + (size_t)r * (IN_F / 2) + kt * 32 + c8 * 4);
            uint4 d = dequant8(v, s, zb);
            *(uint4*)((char*)Bs + row * 128 + ((c8 * 16) ^ ((row & 7) << 4))) = d;
        }
        __syncthreads();

#pragma unroll
        for (int kk = 0; kk < 2; ++kk) {
            short8 a[4], b[4];
#pragma unroll
            for (int mi = 0; mi < 4; ++mi) {
                int row = wm * 64 + mi * 16 + (lane & 15);
                a[mi] = *(const short8*)((const char*)As + row * 128 +
                                         ((kk * 64 + (lane >> 4) * 16) ^ ((row & 7) << 4)));
            }
#pragma unroll
            for (int ni = 0; ni < 4; ++ni) {
                int row = wn * 64 + ni * 16 + (lane & 15);
                b[ni] = *(const short8*)((const char*)Bs + row * 128 +
                                         ((kk * 64 + (lane >> 4) * 16) ^ ((row & 7) << 4)));
            }
#pragma unroll
            for (int mi = 0; mi < 4; ++mi)
#pragma unroll
                for (int ni = 0; ni < 4; ++ni)
                    acc[mi][ni] = __builtin_amdgcn_mfma_f32_16x16x32_bf16(a[mi], b[ni], acc[mi][ni], 0, 0, 0);
        }
        __syncthreads();
    }

#pragma unroll
    for (int ni = 0; ni < 4; ++ni) {
        int col  = bn0 + wn * 64 + ni * 16 + (lane & 15);
        float bv = bias[col];
#pragma unroll
        for (int mi = 0; mi < 4; ++mi) {
            int row0 = bm0 + wm * 64 + mi * 16 + (lane >> 4) * 4;
#pragma unroll
            for (int r = 0; r < 4; ++r)
                out[(size_t)(row0 + r) * OUT_F + col] = acc[mi][ni][r] + bv;
        }
    }
}

extern "C" void kernel_launch(void* const* d_in, const int* in_sizes, int n_in,
                              void* d_out, int out_size, void* d_ws, size_t ws_size,
                              hipStream_t stream) {
    const float* x      = (const float*)d_in[0];
    const int* pw       = (const int*)d_in[1];
    const float* scales = (const float*)d_in[2];
    const int* zps      = (const int*)d_in[3];
    const float* bias   = (const float*)d_in[4];
    float* out          = (float*)d_out;

    const size_t xq_bytes = (size_t)M_DIM * IN_F;        // 32 MiB i8
    const size_t sr_bytes = 65536;                       // srow f32 + pad
    const size_t wq_bytes = (size_t)OUT_F * IN_F;        // ~43 MiB i8
    const bool predeq = ws_size >= xq_bytes + sr_bytes + wq_bytes;

    if (predeq) {
        char*  xq   = (char*)d_ws;
        float* srow = (float*)((char*)d_ws + xq_bytes);
        char*  wq   = (char*)d_ws + xq_bytes + sr_bytes;
        quant_x_kernel<<<dim3(M_DIM), dim3(256), 0, stream>>>(x, xq, srow);
        deqw_i8_kernel<<<dim3(2048), dim3(256), 0, stream>>>(pw, zps, wq, OUT_F * (IN_F / 16));
        (void)hipFuncSetAttribute((const void*)w4a16_gemm_i8,
                                  hipFuncAttributeMaxDynamicSharedMemorySize, 3 * TILE_B);
        w4a16_gemm_i8<<<dim3(NWG), dim3(256), 3 * TILE_B, stream>>>(
            (const uint4*)xq, (const uint4*)wq, srow, scales, bias, out);
    } else {
        w4a16_gemm_fb<<<dim3(FNWG), dim3(256), 0, stream>>>(x, pw, scales, zps, bias, out);
    }
}